// Round 5
// baseline (13445.627 us; speedup 1.0000x reference)
//
#include <hip/hip_runtime.h>
#include <hip/hip_fp16.h>

// Decoder: 2-layer LSTM (H=256), T=512, B=256, scalar output feedback.
// Round 8: attack the measured per-CU VMEM-return-BW ceiling (~47 B/cyc:
// R3 and R4 both land on it despite 2x different VALU load and 2x different
// chip-wide L2 demand -> per-CU fetch pipe is the roofline).
//  - Back to NB=1 / grid=256 (R4's NB=2 bought nothing, idled half the chip).
//  - Register-pin 20 windows of W_ih1 per thread (80 VGPRs, loaded once
//    before the t-loop; constant-index full unroll, regs unaffected by the
//    asm memory fence). Streamed bytes/CU/step: 1.375 MB -> 1.047 MB.
//  - LDS weight cache grown 8 -> 9 windows of W_hh0 (144 KB dynamic; still
//    forces 1 block/CU so 256 blocks cover all 256 CUs).
//  - Keeps: uint4 weight loads, bit_cast->fdot2, LICM fence (round-5
//    spill post-mortem), redundant per-wave pred reduce.

namespace {

constexpr int kB = 256, kT = 512, kH = 256;
constexpr int kWin = 32;                       // 256 k-values / 8 per window
constexpr int kTiles = kWin * 1024;            // uint4 tiles per matrix
constexpr size_t kWsNeeded = 3 * (size_t)kTiles * 16;  // 1.5 MB
constexpr int kLdsWin = 9;                     // whh0 windows in LDS (144 KB)
constexpr int kRegWin = 20;                    // w1i windows in VGPRs (80 regs)

typedef _Float16 h2_t __attribute__((ext_vector_type(2)));
struct alignas(16) H8 { __half2 h[4]; };       // pack-side view of 8 fp16

__device__ __forceinline__ float fsig(float v) { return 1.0f / (1.0f + __expf(-v)); }

// 8-wide fp16 dot-accumulate from two raw uint4 registers.
__device__ __forceinline__ float dot8(uint4 w, uint4 x, float a) {
#if __has_builtin(__builtin_amdgcn_fdot2)
  a = __builtin_amdgcn_fdot2(__builtin_bit_cast(h2_t, w.x),
                             __builtin_bit_cast(h2_t, x.x), a, false);
  a = __builtin_amdgcn_fdot2(__builtin_bit_cast(h2_t, w.y),
                             __builtin_bit_cast(h2_t, x.y), a, false);
  a = __builtin_amdgcn_fdot2(__builtin_bit_cast(h2_t, w.z),
                             __builtin_bit_cast(h2_t, x.z), a, false);
  a = __builtin_amdgcn_fdot2(__builtin_bit_cast(h2_t, w.w),
                             __builtin_bit_cast(h2_t, x.w), a, false);
#else
  {
    float2 f0 = __half22float2(__builtin_bit_cast(__half2, w.x));
    float2 x0 = __half22float2(__builtin_bit_cast(__half2, x.x));
    float2 f1 = __half22float2(__builtin_bit_cast(__half2, w.y));
    float2 x1 = __half22float2(__builtin_bit_cast(__half2, x.y));
    float2 f2 = __half22float2(__builtin_bit_cast(__half2, w.z));
    float2 x2 = __half22float2(__builtin_bit_cast(__half2, x.z));
    float2 f3 = __half22float2(__builtin_bit_cast(__half2, w.w));
    float2 x3 = __half22float2(__builtin_bit_cast(__half2, x.w));
    a = fmaf(f0.x, x0.x, a); a = fmaf(f0.y, x0.y, a);
    a = fmaf(f1.x, x1.x, a); a = fmaf(f1.y, x1.y, a);
    a = fmaf(f2.x, x2.x, a); a = fmaf(f2.y, x2.y, a);
    a = fmaf(f3.x, x3.x, a); a = fmaf(f3.y, x3.y, a);
  }
#endif
  return a;
}

// dst[win*1024 + j] holds w[j][8win..8win+7]; lane-consecutive j => coalesced.
__global__ __launch_bounds__(256) void pack_w(const float* __restrict__ s0,
                                              const float* __restrict__ s1,
                                              const float* __restrict__ s2,
                                              H8* __restrict__ dst) {
  int idx = blockIdx.x * 256 + threadIdx.x;       // 0 .. 3*32768-1
  int mat = idx >> 15;                            // 0..2
  int loc = idx & 32767;                          // win*1024 + j
  int j = loc & 1023, win = loc >> 10;
  const float* src = (mat == 0 ? s0 : (mat == 1 ? s1 : s2)) + j * 256 + win * 8;
  H8 o;
#pragma unroll
  for (int i = 0; i < 4; ++i) o.h[i] = __floats2half2_rn(src[2 * i], src[2 * i + 1]);
  dst[idx] = o;
}

__global__ __launch_bounds__(1024) void decoder_b1(
    const float* __restrict__ seq, const float* __restrict__ z,
    const float* __restrict__ wih0, const float* __restrict__ bih0,
    const float* __restrict__ bhh0, const float* __restrict__ bih1,
    const float* __restrict__ bhh1, const float* __restrict__ wout,
    const float* __restrict__ bout, const uint4* __restrict__ w0,
    const uint4* __restrict__ w1i, const uint4* __restrict__ w1h,
    float* __restrict__ loss_out) {
  extern __shared__ uint4 lw[];                   // kLdsWin windows of whh0
  __shared__ alignas(16) _Float16 h0h[kH];        // hidden, layer 0 (fp16)
  __shared__ alignas(16) _Float16 h1h[kH];        // hidden, layer 1 (fp16)
  __shared__ float g4[1024];
  __shared__ float spred[kH];

  const int tid = threadIdx.x;                    // gate row j
  const int b = blockIdx.x;                       // batch element

  // Stage whh0 windows 0..kLdsWin-1 into LDS (coalesced 16B copies).
#pragma unroll
  for (int i = 0; i < kLdsWin; ++i) lw[i * 1024 + tid] = w0[i * 1024 + tid];

  const uint4* wp0 = w0 + tid;
  const uint4* wpA = w1i + tid;
  const uint4* wpB = w1h + tid;
  const uint4* lwp = lw + tid;

  // Register-pinned w1i windows 0..kRegWin-1 (constant-index full unroll:
  // stays in VGPRs for the whole kernel; 20 x uint4 = 80 regs).
  uint4 rw[kRegWin];
#pragma unroll
  for (int i = 0; i < kRegWin; ++i) rw[i] = wpA[i << 10];

  float c0 = 0.f, c1 = 0.f, woutr = 0.f;
  if (tid < kH) {
    float zv = z[(size_t)b * kH + tid];
    h0h[tid] = (_Float16)zv;
    h1h[tid] = (_Float16)zv;
    c0 = zv;
    c1 = zv;
    woutr = wout[tid];
  }
  const float wih0_j = wih0[tid];
  const float bias0 = bih0[tid] + bhh0[tid];
  const float bias1 = bih1[tid] + bhh1[tid];
  const float bo = bout[0];
  const bool isG = (tid >= 512) && (tid < 768);   // wave-uniform (waves 8..11)
  float xsv = 0.f, lacc = 0.f;

  const uint4* h0u = (const uint4*)h0h;           // 32 windows of 8 halves
  const uint4* h1u = (const uint4*)h1h;
  __syncthreads();

  for (int t = 0; t < kT; ++t) {
    // LICM fence: no loop-invariant LOAD may be hoisted out of the t-loop
    // (round-5 post-mortem). Registers (rw[]) are unaffected by design.
    asm volatile("" ::: "memory");

    // ---- layer 0 gates: Whh0 @ h0 + x*wih0 + bias ----
    float a0 = fmaf(xsv, wih0_j, bias0);
#pragma unroll
    for (int win = 0; win < kLdsWin; ++win)       // LDS-cached windows
      a0 = dot8(lwp[win << 10], h0u[win], a0);
#pragma unroll 4
    for (int win = kLdsWin; win < kWin; ++win)    // L2-streamed windows
      a0 = dot8(wp0[(size_t)win << 10], h0u[win], a0);
    // per-thread nonlinearity: rows 512..767 are gate g (tanh), rest sigmoid
    if (isG) g4[tid] = tanhf(a0); else g4[tid] = fsig(a0);
    __syncthreads();
    if (tid < kH) {
      float gi = g4[tid];
      float gf = g4[tid + 256];
      float gg = g4[tid + 512];
      float go = g4[tid + 768];
      c0 = fmaf(gf, c0, gi * gg);
      h0h[tid] = (_Float16)(go * tanhf(c0));
    }
    __syncthreads();

    // ---- layer 1 gates: Wih1 @ h0new + Whh1 @ h1old ----
    float a1 = bias1;
#pragma unroll
    for (int win = 0; win < kRegWin; ++win) {     // w1i from registers
      uint4 wB = wpB[(size_t)win << 10];          // w1h streamed
      a1 = dot8(rw[win], h0u[win], a1);
      a1 = dot8(wB, h1u[win], a1);
    }
#pragma unroll 2
    for (int win = kRegWin; win < kWin; ++win) {  // both streamed
      uint4 wA = wpA[(size_t)win << 10];
      uint4 wB = wpB[(size_t)win << 10];
      a1 = dot8(wA, h0u[win], a1);
      a1 = dot8(wB, h1u[win], a1);
    }
    if (isG) g4[tid] = tanhf(a1); else g4[tid] = fsig(a1);
    __syncthreads();
    if (tid < kH) {
      float gi = g4[tid];
      float gf = g4[tid + 256];
      float gg = g4[tid + 512];
      float go = g4[tid + 768];
      c1 = fmaf(gf, c1, gi * gg);
      float hn = go * tanhf(c1);                  // fp32, pre-rounding
      h1h[tid] = (_Float16)hn;
      spred[tid] = hn * woutr;                    // pred path stays fp32
    }
    __syncthreads();

    // ---- redundant per-wave reduce: pred stays in-register in every wave ----
    {
      int ln = tid & 63;
      float v = spred[ln] + spred[ln + 64] + spred[ln + 128] + spred[ln + 192];
#pragma unroll
      for (int off = 32; off > 0; off >>= 1) v += __shfl_down(v, off);
      float pred = __shfl(v, 0) + bo;             // broadcast within wave
      xsv = pred;                                 // feedback for next step
      if (tid == 0) {
        float d = seq[(size_t)b * kT + t] - pred;
        lacc = fmaf(d, d, lacc);
      }
    }
    // no barrier needed: next writer of spred passes 3 barriers first
  }

  if (tid == 0) atomicAdd(loss_out, lacc * (1.0f / ((float)kB * (float)kT)));
}

// ---------------- fallback (reads d_in directly, fp32) ---------------------
__global__ __launch_bounds__(1024) void decoder_fallback(
    const float* __restrict__ seq, const float* __restrict__ z,
    const float* __restrict__ wih0, const float* __restrict__ bih0,
    const float* __restrict__ bhh0, const float* __restrict__ whh0,
    const float* __restrict__ wih1, const float* __restrict__ whh1,
    const float* __restrict__ bih1, const float* __restrict__ bhh1,
    const float* __restrict__ wout, const float* __restrict__ bout,
    float* __restrict__ loss_out) {
  __shared__ float h0s[kH], h1s[kH], g4[1024];
  __shared__ float xs_s;
  const int tid = threadIdx.x;
  const int b = blockIdx.x;
  float c0r = 0.f, c1r = 0.f;
  if (tid < kH) {
    float zv = z[b * kH + tid];
    h0s[tid] = zv; h1s[tid] = zv; c0r = zv; c1r = zv;
  }
  if (tid == 0) xs_s = 0.f;
  const float wih0_j = wih0[tid];
  const float bias0_j = bih0[tid] + bhh0[tid];
  const float bias1_j = bih1[tid] + bhh1[tid];
  const float wout_r = (tid < kH) ? wout[tid] : 0.f;
  const float bo = bout[0];
  float lacc = 0.f;
  __syncthreads();
  for (int t = 0; t < kT; ++t) {
    float a0 = fmaf(xs_s, wih0_j, bias0_j);
    for (int k = 0; k < kH; ++k) a0 = fmaf(whh0[tid * kH + k], h0s[k], a0);
    g4[tid] = a0;
    __syncthreads();
    if (tid < kH) {
      float ig = fsig(g4[tid]), fg = fsig(g4[tid + 256]);
      float gg = tanhf(g4[tid + 512]), og = fsig(g4[tid + 768]);
      c0r = fmaf(fg, c0r, ig * gg);
      h0s[tid] = og * tanhf(c0r);
    }
    __syncthreads();
    float a1 = bias1_j;
    for (int k = 0; k < kH; ++k) a1 = fmaf(wih1[tid * kH + k], h0s[k], a1);
    for (int k = 0; k < kH; ++k) a1 = fmaf(whh1[tid * kH + k], h1s[k], a1);
    g4[tid] = a1;
    __syncthreads();
    if (tid < kH) {
      float ig = fsig(g4[tid]), fg = fsig(g4[tid + 256]);
      float gg = tanhf(g4[tid + 512]), og = fsig(g4[tid + 768]);
      c1r = fmaf(fg, c1r, ig * gg);
      float h1 = og * tanhf(c1r);
      h1s[tid] = h1;
      g4[tid] = h1 * wout_r;
    }
    __syncthreads();
    if (tid < 64) {
      float v = g4[tid] + g4[tid + 64] + g4[tid + 128] + g4[tid + 192];
#pragma unroll
      for (int off = 32; off > 0; off >>= 1) v += __shfl_down(v, off);
      if (tid == 0) {
        float pred = v + bo;
        float d = seq[b * kT + t] - pred;
        lacc = fmaf(d, d, lacc);
        xs_s = pred;
      }
    }
    __syncthreads();
  }
  if (tid == 0) atomicAdd(loss_out, lacc * (1.0f / (float)(kB * kT)));
}

}  // namespace

extern "C" void kernel_launch(void* const* d_in, const int* in_sizes, int n_in,
                              void* d_out, int out_size, void* d_ws, size_t ws_size,
                              hipStream_t stream) {
  const float* seq = (const float*)d_in[0];
  const float* z = (const float*)d_in[1];
  const float* wih0 = (const float*)d_in[3];
  const float* whh0 = (const float*)d_in[4];
  const float* bih0 = (const float*)d_in[5];
  const float* bhh0 = (const float*)d_in[6];
  const float* wih1 = (const float*)d_in[7];
  const float* whh1 = (const float*)d_in[8];
  const float* bih1 = (const float*)d_in[9];
  const float* bhh1 = (const float*)d_in[10];
  const float* wout = (const float*)d_in[11];
  const float* bout = (const float*)d_in[12];
  float* out = (float*)d_out;

  hipMemsetAsync(out, 0, sizeof(float), stream);

  if (ws_size >= kWsNeeded) {
    H8* wpk = (H8*)d_ws;  // [3][32768] tiles: whh0, wih1, whh1
    pack_w<<<384, 256, 0, stream>>>(whh0, wih1, whh1, wpk);
    // 144KB dynamic LDS weight cache also forces 1 block/CU -> 256 blocks
    // land on 256 distinct CUs (full machine).
    const uint4* wu = (const uint4*)wpk;
    decoder_b1<<<kB, 1024, kLdsWin * 1024 * (int)sizeof(uint4), stream>>>(
        seq, z, wih0, bih0, bhh0, bih1, bhh1, wout, bout, wu,
        wu + kTiles, wu + 2 * kTiles, out);
  } else {
    decoder_fallback<<<kB, 1024, 0, stream>>>(seq, z, wih0, bih0, bhh0, whh0,
                                              wih1, whh1, bih1, bhh1, wout, bout,
                                              out);
  }
}

// Round 6
// 6220.560 us; speedup vs baseline: 2.1615x; 2.1615x over previous
//
#include <hip/hip_runtime.h>
#include <hip/hip_fp16.h>

// Decoder: 2-layer LSTM (H=256), T=512, B=256, scalar output feedback.
// Round 9: register-pinning retried with the occupancy contract stated.
//  - R5 post-mortem: __launch_bounds__(1024) without min-waves let the
//    allocator cap VGPR at 64 (32-waves/CU budget); the 20 pinned windows
//    spilled to scratch (WRITE 34.8MB, FETCH 10.4GB, 13.4ms).
//  - Fix: __launch_bounds__(1024, 4) = 16 waves/CU = this block exactly;
//    measured occupancy cliffs (64/128/256) make VGPR<=128 free. Pin only
//    16 windows (64 regs) for headroom: base ~32 + 64 ~= 96..112 < 128.
//  - Streamed windows/step: 88 -> 71 (w0:23, w1i:16, w1h:32) = -19% on the
//    measured per-CU VMEM-return-port ceiling (~47 B/cyc, R3/R4 invariant).
//  - Keeps: NB=1 grid=256, uint4 loads, bit_cast->fdot2, LICM fence,
//    kLdsWin=9 (144KB, forces 1 block/CU), redundant per-wave pred reduce.

namespace {

constexpr int kB = 256, kT = 512, kH = 256;
constexpr int kWin = 32;                       // 256 k-values / 8 per window
constexpr int kTiles = kWin * 1024;            // uint4 tiles per matrix
constexpr size_t kWsNeeded = 3 * (size_t)kTiles * 16;  // 1.5 MB
constexpr int kLdsWin = 9;                     // whh0 windows in LDS (144 KB)
constexpr int kRegWin = 16;                    // w1i windows in VGPRs (64 regs)

typedef _Float16 h2_t __attribute__((ext_vector_type(2)));
struct alignas(16) H8 { __half2 h[4]; };       // pack-side view of 8 fp16

__device__ __forceinline__ float fsig(float v) { return 1.0f / (1.0f + __expf(-v)); }

// 8-wide fp16 dot-accumulate from two raw uint4 registers.
__device__ __forceinline__ float dot8(uint4 w, uint4 x, float a) {
#if __has_builtin(__builtin_amdgcn_fdot2)
  a = __builtin_amdgcn_fdot2(__builtin_bit_cast(h2_t, w.x),
                             __builtin_bit_cast(h2_t, x.x), a, false);
  a = __builtin_amdgcn_fdot2(__builtin_bit_cast(h2_t, w.y),
                             __builtin_bit_cast(h2_t, x.y), a, false);
  a = __builtin_amdgcn_fdot2(__builtin_bit_cast(h2_t, w.z),
                             __builtin_bit_cast(h2_t, x.z), a, false);
  a = __builtin_amdgcn_fdot2(__builtin_bit_cast(h2_t, w.w),
                             __builtin_bit_cast(h2_t, x.w), a, false);
#else
  {
    float2 f0 = __half22float2(__builtin_bit_cast(__half2, w.x));
    float2 x0 = __half22float2(__builtin_bit_cast(__half2, x.x));
    float2 f1 = __half22float2(__builtin_bit_cast(__half2, w.y));
    float2 x1 = __half22float2(__builtin_bit_cast(__half2, x.y));
    float2 f2 = __half22float2(__builtin_bit_cast(__half2, w.z));
    float2 x2 = __half22float2(__builtin_bit_cast(__half2, x.z));
    float2 f3 = __half22float2(__builtin_bit_cast(__half2, w.w));
    float2 x3 = __half22float2(__builtin_bit_cast(__half2, x.w));
    a = fmaf(f0.x, x0.x, a); a = fmaf(f0.y, x0.y, a);
    a = fmaf(f1.x, x1.x, a); a = fmaf(f1.y, x1.y, a);
    a = fmaf(f2.x, x2.x, a); a = fmaf(f2.y, x2.y, a);
    a = fmaf(f3.x, x3.x, a); a = fmaf(f3.y, x3.y, a);
  }
#endif
  return a;
}

// dst[win*1024 + j] holds w[j][8win..8win+7]; lane-consecutive j => coalesced.
__global__ __launch_bounds__(256) void pack_w(const float* __restrict__ s0,
                                              const float* __restrict__ s1,
                                              const float* __restrict__ s2,
                                              H8* __restrict__ dst) {
  int idx = blockIdx.x * 256 + threadIdx.x;       // 0 .. 3*32768-1
  int mat = idx >> 15;                            // 0..2
  int loc = idx & 32767;                          // win*1024 + j
  int j = loc & 1023, win = loc >> 10;
  const float* src = (mat == 0 ? s0 : (mat == 1 ? s1 : s2)) + j * 256 + win * 8;
  H8 o;
#pragma unroll
  for (int i = 0; i < 4; ++i) o.h[i] = __floats2half2_rn(src[2 * i], src[2 * i + 1]);
  dst[idx] = o;
}

__global__ __launch_bounds__(1024, 4) void decoder_b1(
    const float* __restrict__ seq, const float* __restrict__ z,
    const float* __restrict__ wih0, const float* __restrict__ bih0,
    const float* __restrict__ bhh0, const float* __restrict__ bih1,
    const float* __restrict__ bhh1, const float* __restrict__ wout,
    const float* __restrict__ bout, const uint4* __restrict__ w0,
    const uint4* __restrict__ w1i, const uint4* __restrict__ w1h,
    float* __restrict__ loss_out) {
  extern __shared__ uint4 lw[];                   // kLdsWin windows of whh0
  __shared__ alignas(16) _Float16 h0h[kH];        // hidden, layer 0 (fp16)
  __shared__ alignas(16) _Float16 h1h[kH];        // hidden, layer 1 (fp16)
  __shared__ float g4[1024];
  __shared__ float spred[kH];

  const int tid = threadIdx.x;                    // gate row j
  const int b = blockIdx.x;                       // batch element

  // Stage whh0 windows 0..kLdsWin-1 into LDS (coalesced 16B copies).
#pragma unroll
  for (int i = 0; i < kLdsWin; ++i) lw[i * 1024 + tid] = w0[i * 1024 + tid];

  const uint4* wp0 = w0 + tid;
  const uint4* wpA = w1i + tid;
  const uint4* wpB = w1h + tid;
  const uint4* lwp = lw + tid;

  // Register-pinned w1i windows 0..kRegWin-1 (constant-index full unroll;
  // 16 x uint4 = 64 regs; launch_bounds(1024,4) grants the 128-reg budget).
  uint4 rw[kRegWin];
#pragma unroll
  for (int i = 0; i < kRegWin; ++i) rw[i] = wpA[i << 10];

  float c0 = 0.f, c1 = 0.f, woutr = 0.f;
  if (tid < kH) {
    float zv = z[(size_t)b * kH + tid];
    h0h[tid] = (_Float16)zv;
    h1h[tid] = (_Float16)zv;
    c0 = zv;
    c1 = zv;
    woutr = wout[tid];
  }
  const float wih0_j = wih0[tid];
  const float bias0 = bih0[tid] + bhh0[tid];
  const float bias1 = bih1[tid] + bhh1[tid];
  const float bo = bout[0];
  const bool isG = (tid >= 512) && (tid < 768);   // wave-uniform (waves 8..11)
  float xsv = 0.f, lacc = 0.f;

  const uint4* h0u = (const uint4*)h0h;           // 32 windows of 8 halves
  const uint4* h1u = (const uint4*)h1h;
  __syncthreads();

  for (int t = 0; t < kT; ++t) {
    // LICM fence: no loop-invariant LOAD may be hoisted out of the t-loop
    // (round-5 post-mortem). Registers (rw[]) are unaffected by design.
    asm volatile("" ::: "memory");

    // ---- layer 0 gates: Whh0 @ h0 + x*wih0 + bias ----
    float a0 = fmaf(xsv, wih0_j, bias0);
#pragma unroll
    for (int win = 0; win < kLdsWin; ++win)       // LDS-cached windows
      a0 = dot8(lwp[win << 10], h0u[win], a0);
#pragma unroll 4
    for (int win = kLdsWin; win < kWin; ++win)    // L2-streamed windows
      a0 = dot8(wp0[(size_t)win << 10], h0u[win], a0);
    // per-thread nonlinearity: rows 512..767 are gate g (tanh), rest sigmoid
    if (isG) g4[tid] = tanhf(a0); else g4[tid] = fsig(a0);
    __syncthreads();
    if (tid < kH) {
      float gi = g4[tid];
      float gf = g4[tid + 256];
      float gg = g4[tid + 512];
      float go = g4[tid + 768];
      c0 = fmaf(gf, c0, gi * gg);
      h0h[tid] = (_Float16)(go * tanhf(c0));
    }
    __syncthreads();

    // ---- layer 1 gates: Wih1 @ h0new + Whh1 @ h1old ----
    float a1 = bias1;
#pragma unroll
    for (int win = 0; win < kRegWin; ++win) {     // w1i from registers
      uint4 wB = wpB[(size_t)win << 10];          // w1h streamed
      a1 = dot8(rw[win], h0u[win], a1);
      a1 = dot8(wB, h1u[win], a1);
    }
#pragma unroll 2
    for (int win = kRegWin; win < kWin; ++win) {  // both streamed
      uint4 wA = wpA[(size_t)win << 10];
      uint4 wB = wpB[(size_t)win << 10];
      a1 = dot8(wA, h0u[win], a1);
      a1 = dot8(wB, h1u[win], a1);
    }
    if (isG) g4[tid] = tanhf(a1); else g4[tid] = fsig(a1);
    __syncthreads();
    if (tid < kH) {
      float gi = g4[tid];
      float gf = g4[tid + 256];
      float gg = g4[tid + 512];
      float go = g4[tid + 768];
      c1 = fmaf(gf, c1, gi * gg);
      float hn = go * tanhf(c1);                  // fp32, pre-rounding
      h1h[tid] = (_Float16)hn;
      spred[tid] = hn * woutr;                    // pred path stays fp32
    }
    __syncthreads();

    // ---- redundant per-wave reduce: pred stays in-register in every wave ----
    {
      int ln = tid & 63;
      float v = spred[ln] + spred[ln + 64] + spred[ln + 128] + spred[ln + 192];
#pragma unroll
      for (int off = 32; off > 0; off >>= 1) v += __shfl_down(v, off);
      float pred = __shfl(v, 0) + bo;             // broadcast within wave
      xsv = pred;                                 // feedback for next step
      if (tid == 0) {
        float d = seq[(size_t)b * kT + t] - pred;
        lacc = fmaf(d, d, lacc);
      }
    }
    // no barrier needed: next writer of spred passes 3 barriers first
  }

  if (tid == 0) atomicAdd(loss_out, lacc * (1.0f / ((float)kB * (float)kT)));
}

// ---------------- fallback (reads d_in directly, fp32) ---------------------
__global__ __launch_bounds__(1024) void decoder_fallback(
    const float* __restrict__ seq, const float* __restrict__ z,
    const float* __restrict__ wih0, const float* __restrict__ bih0,
    const float* __restrict__ bhh0, const float* __restrict__ whh0,
    const float* __restrict__ wih1, const float* __restrict__ whh1,
    const float* __restrict__ bih1, const float* __restrict__ bhh1,
    const float* __restrict__ wout, const float* __restrict__ bout,
    float* __restrict__ loss_out) {
  __shared__ float h0s[kH], h1s[kH], g4[1024];
  __shared__ float xs_s;
  const int tid = threadIdx.x;
  const int b = blockIdx.x;
  float c0r = 0.f, c1r = 0.f;
  if (tid < kH) {
    float zv = z[b * kH + tid];
    h0s[tid] = zv; h1s[tid] = zv; c0r = zv; c1r = zv;
  }
  if (tid == 0) xs_s = 0.f;
  const float wih0_j = wih0[tid];
  const float bias0_j = bih0[tid] + bhh0[tid];
  const float bias1_j = bih1[tid] + bhh1[tid];
  const float wout_r = (tid < kH) ? wout[tid] : 0.f;
  const float bo = bout[0];
  float lacc = 0.f;
  __syncthreads();
  for (int t = 0; t < kT; ++t) {
    float a0 = fmaf(xs_s, wih0_j, bias0_j);
    for (int k = 0; k < kH; ++k) a0 = fmaf(whh0[tid * kH + k], h0s[k], a0);
    g4[tid] = a0;
    __syncthreads();
    if (tid < kH) {
      float ig = fsig(g4[tid]), fg = fsig(g4[tid + 256]);
      float gg = tanhf(g4[tid + 512]), og = fsig(g4[tid + 768]);
      c0r = fmaf(fg, c0r, ig * gg);
      h0s[tid] = og * tanhf(c0r);
    }
    __syncthreads();
    float a1 = bias1_j;
    for (int k = 0; k < kH; ++k) a1 = fmaf(wih1[tid * kH + k], h0s[k], a1);
    for (int k = 0; k < kH; ++k) a1 = fmaf(whh1[tid * kH + k], h1s[k], a1);
    g4[tid] = a1;
    __syncthreads();
    if (tid < kH) {
      float ig = fsig(g4[tid]), fg = fsig(g4[tid + 256]);
      float gg = tanhf(g4[tid + 512]), og = fsig(g4[tid + 768]);
      c1r = fmaf(fg, c1r, ig * gg);
      float h1 = og * tanhf(c1r);
      h1s[tid] = h1;
      g4[tid] = h1 * wout_r;
    }
    __syncthreads();
    if (tid < 64) {
      float v = g4[tid] + g4[tid + 64] + g4[tid + 128] + g4[tid + 192];
#pragma unroll
      for (int off = 32; off > 0; off >>= 1) v += __shfl_down(v, off);
      if (tid == 0) {
        float pred = v + bo;
        float d = seq[b * kT + t] - pred;
        lacc = fmaf(d, d, lacc);
        xs_s = pred;
      }
    }
    __syncthreads();
  }
  if (tid == 0) atomicAdd(loss_out, lacc * (1.0f / (float)(kB * kT)));
}

}  // namespace

extern "C" void kernel_launch(void* const* d_in, const int* in_sizes, int n_in,
                              void* d_out, int out_size, void* d_ws, size_t ws_size,
                              hipStream_t stream) {
  const float* seq = (const float*)d_in[0];
  const float* z = (const float*)d_in[1];
  const float* wih0 = (const float*)d_in[3];
  const float* whh0 = (const float*)d_in[4];
  const float* bih0 = (const float*)d_in[5];
  const float* bhh0 = (const float*)d_in[6];
  const float* wih1 = (const float*)d_in[7];
  const float* whh1 = (const float*)d_in[8];
  const float* bih1 = (const float*)d_in[9];
  const float* bhh1 = (const float*)d_in[10];
  const float* wout = (const float*)d_in[11];
  const float* bout = (const float*)d_in[12];
  float* out = (float*)d_out;

  hipMemsetAsync(out, 0, sizeof(float), stream);

  if (ws_size >= kWsNeeded) {
    H8* wpk = (H8*)d_ws;  // [3][32768] tiles: whh0, wih1, whh1
    pack_w<<<384, 256, 0, stream>>>(whh0, wih1, whh1, wpk);
    // 144KB dynamic LDS weight cache also forces 1 block/CU -> 256 blocks
    // land on 256 distinct CUs (full machine).
    const uint4* wu = (const uint4*)wpk;
    decoder_b1<<<kB, 1024, kLdsWin * 1024 * (int)sizeof(uint4), stream>>>(
        seq, z, wih0, bih0, bhh0, bih1, bhh1, wout, bout, wu,
        wu + kTiles, wu + 2 * kTiles, out);
  } else {
    decoder_fallback<<<kB, 1024, 0, stream>>>(seq, z, wih0, bih0, bhh0, whh0,
                                              wih1, whh1, bih1, bhh1, wout, bout,
                                              out);
  }
}

// Round 7
// 4590.405 us; speedup vs baseline: 2.9291x; 1.3551x over previous
//
#include <hip/hip_runtime.h>
#include <hip/hip_fp16.h>

// Decoder: 2-layer LSTM (H=256), T=512, B=256, scalar output feedback.
// Round 10: u8 weight quantization (per-row scale) to halve the saturated
// per-CU VMEM-return port traffic (~47 B/cyc measured invariant across
// R3/R4/R6; register pinning proven useless since scratch reloads use the
// same port).
//  - Weights packed to u8 with per-row scale s_j = max|row|/127, biased +128.
//  - Decode: v_perm_b32 embeds byte q as exact fp16 (1024+q) = 0x6400|q.
//    Dot stays fdot2 vs fp16 h; algebra: sum w*h = s_j*(D - 1152*sum_h),
//    with D = sum (1024+q)*h and sum_h one wave-redundant reduce per layer.
//  - Streamed bytes/CU/step: 1.36 MB -> 624 KB (whh0: 7/16 bigwins streamed,
//    9 cached in 144 KB LDS; w1i, w1h fully streamed at 8 bits).
//  - Keeps R3's proven skeleton: NB=1 grid=256, uint4 loads, LICM fence,
//    1 block/CU via LDS footprint, redundant per-wave pred reduce.

namespace {

constexpr int kB = 256, kT = 512, kH = 256;
constexpr int kBW = 16;                     // big-windows of 16 k per matrix
constexpr int kLdsBW = 9;                   // whh0 bigwins in LDS (144 KB)
constexpr int kU4PerMat = kBW * 1024;       // 16384 uint4 per matrix
constexpr size_t kWsNeeded =
    3 * (size_t)kU4PerMat * 16 + 3 * 1024 * 4;  // 786432 + 12288 = 798720

typedef _Float16 h2_t __attribute__((ext_vector_type(2)));

__device__ __forceinline__ float fsig(float v) { return 1.0f / (1.0f + __expf(-v)); }

__device__ __forceinline__ float fdot2f(uint a, uint b, float acc) {
#if __has_builtin(__builtin_amdgcn_fdot2)
  return __builtin_amdgcn_fdot2(__builtin_bit_cast(h2_t, a),
                                __builtin_bit_cast(h2_t, b), acc, false);
#else
  float2 fa = __half22float2(__builtin_bit_cast(__half2, a));
  float2 fb = __half22float2(__builtin_bit_cast(__half2, b));
  return fmaf(fa.y, fb.y, fmaf(fa.x, fb.x, acc));
#endif
}

// Expand byte-pair of q into half2 {1024+b_lo, 1024+b_hi} (exact in fp16).
__device__ __forceinline__ uint q2h_lo(uint q) {
#if __has_builtin(__builtin_amdgcn_perm)
  return __builtin_amdgcn_perm(0x64646464u, q, 0x04010400u);  // {b0,64,b1,64}
#else
  return 0x64006400u | (q & 0xFFu) | ((q & 0xFF00u) << 8);
#endif
}
__device__ __forceinline__ uint q2h_hi(uint q) {
#if __has_builtin(__builtin_amdgcn_perm)
  return __builtin_amdgcn_perm(0x64646464u, q, 0x04030402u);  // {b2,64,b3,64}
#else
  return 0x64006400u | ((q >> 16) & 0xFFu) | ((q >> 8) & 0xFF0000u);
#endif
}

// 16-wide u8-weight dot vs fp16 h: accumulates D = sum (1024+q_k)*h_k.
__device__ __forceinline__ float dot16(uint4 q, uint4 hA, uint4 hB, float D) {
  D = fdot2f(q2h_lo(q.x), hA.x, D);
  D = fdot2f(q2h_hi(q.x), hA.y, D);
  D = fdot2f(q2h_lo(q.y), hA.z, D);
  D = fdot2f(q2h_hi(q.y), hA.w, D);
  D = fdot2f(q2h_lo(q.z), hB.x, D);
  D = fdot2f(q2h_hi(q.z), hB.y, D);
  D = fdot2f(q2h_lo(q.w), hB.z, D);
  D = fdot2f(q2h_hi(q.w), hB.w, D);
  return D;
}

// One wave-row per matrix row: per-row absmax -> scale, quantize 256 w to u8.
// dst layout (u32 view, per matrix): [bw(16)][j(1024)][c(4)], bytes of
// k = 16*bw + 4*c .. +3. Main loop reads uint4 tile[bw*1024 + j].
__global__ __launch_bounds__(64) void pack_q(const float* __restrict__ s0,
                                             const float* __restrict__ s1,
                                             const float* __restrict__ s2,
                                             uint* __restrict__ dst,
                                             float* __restrict__ scl) {
  int r = blockIdx.x;                 // 0..3071
  int mat = r >> 10, j = r & 1023;
  int ln = threadIdx.x;               // 0..63, covers k = 4*ln..4*ln+3
  const float* src = (mat == 0 ? s0 : (mat == 1 ? s1 : s2)) + j * 256 + ln * 4;
  float4 v = *(const float4*)src;
  float m = fmaxf(fmaxf(fabsf(v.x), fabsf(v.y)), fmaxf(fabsf(v.z), fabsf(v.w)));
#pragma unroll
  for (int off = 32; off > 0; off >>= 1) m = fmaxf(m, __shfl_xor(m, off));
  float rcp = (m > 0.f) ? 127.0f / m : 0.f;
  uint q0 = (uint)(__float2int_rn(v.x * rcp) + 128);
  uint q1 = (uint)(__float2int_rn(v.y * rcp) + 128);
  uint q2 = (uint)(__float2int_rn(v.z * rcp) + 128);
  uint q3 = (uint)(__float2int_rn(v.w * rcp) + 128);
  uint packed = q0 | (q1 << 8) | (q2 << 16) | (q3 << 24);
  dst[mat * 65536 + (ln >> 2) * 4096 + j * 4 + (ln & 3)] = packed;
  if (ln == 0) scl[mat * 1024 + j] = m * (1.0f / 127.0f);
}

__global__ __launch_bounds__(1024) void decoder_q8(
    const float* __restrict__ seq, const float* __restrict__ z,
    const float* __restrict__ wih0, const float* __restrict__ bih0,
    const float* __restrict__ bhh0, const float* __restrict__ bih1,
    const float* __restrict__ bhh1, const float* __restrict__ wout,
    const float* __restrict__ bout, const uint4* __restrict__ w0,
    const uint4* __restrict__ w1i, const uint4* __restrict__ w1h,
    const float* __restrict__ scl, float* __restrict__ loss_out) {
  extern __shared__ uint4 lw[];                   // kLdsBW bigwins of whh0
  __shared__ alignas(16) _Float16 h0h[kH];        // hidden, layer 0 (fp16)
  __shared__ alignas(16) _Float16 h1h[kH];        // hidden, layer 1 (fp16)
  __shared__ float g4[1024];
  __shared__ float spred[kH];

  const int tid = threadIdx.x;                    // gate row j
  const int b = blockIdx.x;                       // batch element

  // Stage whh0 bigwins 0..kLdsBW-1 into LDS (coalesced 16B copies).
#pragma unroll
  for (int i = 0; i < kLdsBW; ++i) lw[i * 1024 + tid] = w0[i * 1024 + tid];

  float c0 = 0.f, c1 = 0.f, woutr = 0.f;
  if (tid < kH) {
    float zv = z[(size_t)b * kH + tid];
    h0h[tid] = (_Float16)zv;
    h1h[tid] = (_Float16)zv;
    c0 = zv;
    c1 = zv;
    woutr = wout[tid];
  }
  const float wih0_j = wih0[tid];
  const float bias0 = bih0[tid] + bhh0[tid];
  const float bias1 = bih1[tid] + bhh1[tid];
  const float s0j = scl[tid];
  const float s1ij = scl[1024 + tid];
  const float s1hj = scl[2048 + tid];
  const float bo = bout[0];
  const bool isG = (tid >= 512) && (tid < 768);   // wave-uniform (waves 8..11)
  float xsv = 0.f, lacc = 0.f;

  const uint4* wp0 = w0 + tid;
  const uint4* wpA = w1i + tid;
  const uint4* wpB = w1h + tid;
  const uint4* lwp = lw + tid;
  const uint4* h0u = (const uint4*)h0h;           // 2 uint4 per bigwin
  const uint4* h1u = (const uint4*)h1h;
  const uint2* h0d = (const uint2*)h0h;           // 64 uint2 = 256 halves
  const uint2* h1d = (const uint2*)h1h;
  const uint ONES = 0x3C003C00u;                  // half2 {1.0, 1.0}
  __syncthreads();

  // Initial sums of h0/h1 (both equal sum of z), wave-redundant reduce.
  float sh0, sh1;
  {
    uint2 u = h0d[tid & 63];
    float p = fdot2f(u.y, ONES, fdot2f(u.x, ONES, 0.f));
#pragma unroll
    for (int off = 32; off > 0; off >>= 1) p += __shfl_xor(p, off);
    sh0 = p;
    sh1 = p;
  }

  for (int t = 0; t < kT; ++t) {
    // LICM fence (round-5 post-mortem: hoist->spill->scratch-bound).
    asm volatile("" ::: "memory");

    // ---- layer 0: D0 = sum (1024+q)*h0 over 256 k ----
    float D0 = 0.f;
#pragma unroll
    for (int bw = 0; bw < kLdsBW; ++bw)           // LDS-cached bigwins
      D0 = dot16(lwp[bw << 10], h0u[2 * bw], h0u[2 * bw + 1], D0);
#pragma unroll 4
    for (int bw = kLdsBW; bw < kBW; ++bw)         // L2-streamed bigwins
      D0 = dot16(wp0[(size_t)bw << 10], h0u[2 * bw], h0u[2 * bw + 1], D0);
    float a0 = fmaf(xsv, wih0_j, bias0) + s0j * fmaf(-1152.f, sh0, D0);
    g4[tid] = isG ? tanhf(a0) : fsig(a0);
    __syncthreads();
    if (tid < kH) {
      float gi = g4[tid];
      float gf = g4[tid + 256];
      float gg = g4[tid + 512];
      float go = g4[tid + 768];
      c0 = fmaf(gf, c0, gi * gg);
      h0h[tid] = (_Float16)(go * tanhf(c0));
    }
    __syncthreads();

    // new sum of h0 (serves this step's layer 1 and next step's layer 0)
    {
      uint2 u = h0d[tid & 63];
      float p = fdot2f(u.y, ONES, fdot2f(u.x, ONES, 0.f));
#pragma unroll
      for (int off = 32; off > 0; off >>= 1) p += __shfl_xor(p, off);
      sh0 = p;
    }

    // ---- layer 1: D1i = sum(1024+q1i)*h0new, D1h = sum(1024+q1h)*h1old ----
    float D1i = 0.f, D1h = 0.f;
#pragma unroll 2
    for (int bw = 0; bw < kBW; ++bw) {
      uint4 qA = wpA[(size_t)bw << 10];
      uint4 qB = wpB[(size_t)bw << 10];
      D1i = dot16(qA, h0u[2 * bw], h0u[2 * bw + 1], D1i);
      D1h = dot16(qB, h1u[2 * bw], h1u[2 * bw + 1], D1h);
    }
    float a1 = bias1 + s1ij * fmaf(-1152.f, sh0, D1i) +
               s1hj * fmaf(-1152.f, sh1, D1h);
    g4[tid] = isG ? tanhf(a1) : fsig(a1);
    __syncthreads();
    if (tid < kH) {
      float gi = g4[tid];
      float gf = g4[tid + 256];
      float gg = g4[tid + 512];
      float go = g4[tid + 768];
      c1 = fmaf(gf, c1, gi * gg);
      float hn = go * tanhf(c1);                  // fp32, pre-rounding
      h1h[tid] = (_Float16)hn;
      spred[tid] = hn * woutr;                    // pred path stays fp32
    }
    __syncthreads();

    // ---- pred reduce (redundant per wave) + new sum of h1 ----
    {
      int ln = tid & 63;
      float v = spred[ln] + spred[ln + 64] + spred[ln + 128] + spred[ln + 192];
#pragma unroll
      for (int off = 32; off > 0; off >>= 1) v += __shfl_down(v, off);
      float pred = __shfl(v, 0) + bo;             // broadcast within wave
      xsv = pred;                                 // feedback for next step
      if (tid == 0) {
        float d = seq[(size_t)b * kT + t] - pred;
        lacc = fmaf(d, d, lacc);
      }
      uint2 u = h1d[ln];
      float p = fdot2f(u.y, ONES, fdot2f(u.x, ONES, 0.f));
#pragma unroll
      for (int off = 32; off > 0; off >>= 1) p += __shfl_xor(p, off);
      sh1 = p;
    }
    // no extra barrier: next writer of spred/h passes 2+ barriers first
  }

  if (tid == 0) atomicAdd(loss_out, lacc * (1.0f / ((float)kB * (float)kT)));
}

// ---------------- fallback (reads d_in directly, fp32) ---------------------
__global__ __launch_bounds__(1024) void decoder_fallback(
    const float* __restrict__ seq, const float* __restrict__ z,
    const float* __restrict__ wih0, const float* __restrict__ bih0,
    const float* __restrict__ bhh0, const float* __restrict__ whh0,
    const float* __restrict__ wih1, const float* __restrict__ whh1,
    const float* __restrict__ bih1, const float* __restrict__ bhh1,
    const float* __restrict__ wout, const float* __restrict__ bout,
    float* __restrict__ loss_out) {
  __shared__ float h0s[kH], h1s[kH], g4[1024];
  __shared__ float xs_s;
  const int tid = threadIdx.x;
  const int b = blockIdx.x;
  float c0r = 0.f, c1r = 0.f;
  if (tid < kH) {
    float zv = z[b * kH + tid];
    h0s[tid] = zv; h1s[tid] = zv; c0r = zv; c1r = zv;
  }
  if (tid == 0) xs_s = 0.f;
  const float wih0_j = wih0[tid];
  const float bias0_j = bih0[tid] + bhh0[tid];
  const float bias1_j = bih1[tid] + bhh1[tid];
  const float wout_r = (tid < kH) ? wout[tid] : 0.f;
  const float bo = bout[0];
  float lacc = 0.f;
  __syncthreads();
  for (int t = 0; t < kT; ++t) {
    float a0 = fmaf(xs_s, wih0_j, bias0_j);
    for (int k = 0; k < kH; ++k) a0 = fmaf(whh0[tid * kH + k], h0s[k], a0);
    g4[tid] = a0;
    __syncthreads();
    if (tid < kH) {
      float ig = fsig(g4[tid]), fg = fsig(g4[tid + 256]);
      float gg = tanhf(g4[tid + 512]), og = fsig(g4[tid + 768]);
      c0r = fmaf(fg, c0r, ig * gg);
      h0s[tid] = og * tanhf(c0r);
    }
    __syncthreads();
    float a1 = bias1_j;
    for (int k = 0; k < kH; ++k) a1 = fmaf(wih1[tid * kH + k], h0s[k], a1);
    for (int k = 0; k < kH; ++k) a1 = fmaf(whh1[tid * kH + k], h1s[k], a1);
    g4[tid] = a1;
    __syncthreads();
    if (tid < kH) {
      float ig = fsig(g4[tid]), fg = fsig(g4[tid + 256]);
      float gg = tanhf(g4[tid + 512]), og = fsig(g4[tid + 768]);
      c1r = fmaf(fg, c1r, ig * gg);
      float h1 = og * tanhf(c1r);
      h1s[tid] = h1;
      g4[tid] = h1 * wout_r;
    }
    __syncthreads();
    if (tid < 64) {
      float v = g4[tid] + g4[tid + 64] + g4[tid + 128] + g4[tid + 192];
#pragma unroll
      for (int off = 32; off > 0; off >>= 1) v += __shfl_down(v, off);
      if (tid == 0) {
        float pred = v + bo;
        float d = seq[b * kT + t] - pred;
        lacc = fmaf(d, d, lacc);
        xs_s = pred;
      }
    }
    __syncthreads();
  }
  if (tid == 0) atomicAdd(loss_out, lacc * (1.0f / (float)(kB * kT)));
}

}  // namespace

extern "C" void kernel_launch(void* const* d_in, const int* in_sizes, int n_in,
                              void* d_out, int out_size, void* d_ws, size_t ws_size,
                              hipStream_t stream) {
  const float* seq = (const float*)d_in[0];
  const float* z = (const float*)d_in[1];
  const float* wih0 = (const float*)d_in[3];
  const float* whh0 = (const float*)d_in[4];
  const float* bih0 = (const float*)d_in[5];
  const float* bhh0 = (const float*)d_in[6];
  const float* wih1 = (const float*)d_in[7];
  const float* whh1 = (const float*)d_in[8];
  const float* bih1 = (const float*)d_in[9];
  const float* bhh1 = (const float*)d_in[10];
  const float* wout = (const float*)d_in[11];
  const float* bout = (const float*)d_in[12];
  float* out = (float*)d_out;

  hipMemsetAsync(out, 0, sizeof(float), stream);

  if (ws_size >= kWsNeeded) {
    uint* wq = (uint*)d_ws;                 // [3][65536] u32 of u8 weights
    float* scl = (float*)(wq + 3 * 65536);  // [3][1024] per-row scales
    pack_q<<<3072, 64, 0, stream>>>(whh0, wih1, whh1, wq, scl);
    // 144KB dynamic LDS weight cache also forces 1 block/CU -> 256 blocks
    // land on 256 distinct CUs (full machine).
    const uint4* wu = (const uint4*)wq;
    decoder_q8<<<kB, 1024, kLdsBW * 1024 * (int)sizeof(uint4), stream>>>(
        seq, z, wih0, bih0, bhh0, bih1, bhh1, wout, bout, wu,
        wu + kU4PerMat, wu + 2 * kU4PerMat, scl, out);
  } else {
    decoder_fallback<<<kB, 1024, 0, stream>>>(seq, z, wih0, bih0, bhh0, whh0,
                                              wih1, whh1, bih1, bhh1, wout, bout,
                                              out);
  }
}